// Round 1
// baseline (178.699 us; speedup 1.0000x reference)
//
#include <hip/hip_runtime.h>

// ---------------------------------------------------------------------------
// SSIM, full-width strip kernel (R3 rewrite of the 166 µs / 56.5 µs R2-best).
//
// R2 structure: 126x15 tiles -> y-fetch amp 1.42x, 132/256 lanes in vertical,
// 4x b32 LDS writes/stat-row, bounds check on every load.
// R3:
//  * block = full image width: 384 thr, 1 col each. x-amp 1.0, no col clips,
//    vertical pass 100% lane-active.
//  * 8 y-strips (49/35 out rows) x 128 images = 1024 blocks; 7-row register
//    ring buffer slides down the strip -> y-amp 426/384 = 1.109 (was 1.42).
//    All loads provably in-bounds (max row = 383) -> zero bounds checks.
//  * chunk = 7 out rows so ring slot (i+6)%7 is a compile-time constant.
//  * stats in two float2 LDS planes (sx,sy | sq,sxy): ds_write_b64 halves
//    write insts; reads 16x ds_read_b128 per slot. Pitch P2=394 float2:
//    row stride 788 words == 20 mod 32 -> 7 rows on 7 distinct bank quads.
//  * SSIM math / constants / rcpf / select-masking verbatim from R2.
// Predicted: ssim_main ~36 us (fetch 167 MB -> 26.6 us floor, LDS ~15 us,
// VALU ~10 us, overlapped). LDS 44.1 KB -> 3 blocks/CU (18 waves).
// ---------------------------------------------------------------------------

#define H 384
#define W 384
#define OWIDTH 378          // valid output rows/cols per image
#define NIMG 128
#define CH 7                // chunk rows (== WIN so ring slots are static)
#define P2 394              // LDS row pitch in float2 (>=392 needed; bank-spread)
#define PLANE (CH * P2)     // 2758 float2 per plane
#define SY 49               // out rows per full strip (7 chunks)
#define NSTRIP 8            // 7*49 + 35 = 378
#define NBLK (NSTRIP * NIMG)  // 1024 partials
#define NGRP 48             // horizontal groups of 8 outputs (48*8 >= 378)
#define NSLOT (NGRP * CH)   // 336 active threads in horizontal phase

__device__ __forceinline__ float wave_reduce(float v) {
#pragma unroll
    for (int off = 32; off > 0; off >>= 1) v += __shfl_down(v, off, 64);
    return v;
}

// Vertical sliding-window step: retire ring slot SLOT (row leaving window),
// load-in values XN/YN (row entering), update 4 running stats, store stat row
// LR to LDS. SLOT/LR must be compile-time constants (no scratch).
#define VSTEP(SLOT, LR, XN, YN) do {                                      \
    const float xo = xv[SLOT], yo = yv[SLOT];                             \
    const float xn = (XN), yn = (YN);                                     \
    sx += xn - xo; sy += yn - yo;                                         \
    sq = fmaf(xn, xn, fmaf(yn, yn, fmaf(-xo, xo, fmaf(-yo, yo, sq))));    \
    sxy = fmaf(xn, yn, fmaf(-xo, yo, sxy));                               \
    xv[SLOT] = xn; yv[SLOT] = yn;                                         \
    stA[(LR) * P2 + t] = make_float2(sx, sy);                             \
    stB[(LR) * P2 + t] = make_float2(sq, sxy);                            \
} while (0)

__global__ __launch_bounds__(384, 5) void ssim_main(const float* __restrict__ pred,
                                                    const float* __restrict__ act,
                                                    float* __restrict__ partials) {
    __shared__ __align__(16) float2 st[2 * PLANE];   // 44128 B -> 3 blocks/CU
    __shared__ float red[6];

    const int t = threadIdx.x;
    const int y0 = blockIdx.x * SY;
    const int nrows = (blockIdx.x == NSTRIP - 1) ? (OWIDTH - (NSTRIP - 1) * SY) : SY; // 35 : 49
    const int nch = nrows / CH;                       // 5 or 7
    const size_t base = (size_t)blockIdx.y * (H * W);

    float2* const stA = st;
    float2* const stB = st + PLANE;

    // column owned by this thread; all row accesses y0..y0+nrows+5 <= 383.
    const float* xp = pred + base + (size_t)y0 * W + t;
    const float* ap = act  + base + (size_t)y0 * W + t;

    // horizontal-phase constants (valid for t < NSLOT)
    const int g = t / 7;            // 0..47  column group -> outputs 8g..8g+7
    const int r = t - 7 * g;        // 0..6   chunk row
    const int c0 = g * 8;
    const int nmax = OWIDTH - c0;   // valid outputs in this group (g=47 -> 2)
    const float C1B = 0.2401f;      // C1 * 49^2
    const float C2B = 2.1168f;      // C2 * 48*49
    float acc = 0.f;

    // ---------------- vertical prologue + chunk 0 ----------------
    float xv[7], yv[7];
    float sx = 0.f, sy = 0.f, sq = 0.f, sxy = 0.f;
#pragma unroll
    for (int i = 0; i < 7; ++i) {
        xv[i] = xp[i * W];
        yv[i] = ap[i * W];
    }
#pragma unroll
    for (int i = 0; i < 7; ++i) {
        sx += xv[i]; sy += yv[i];
        sq = fmaf(xv[i], xv[i], fmaf(yv[i], yv[i], sq));
        sxy = fmaf(xv[i], yv[i], sxy);
    }
    stA[t] = make_float2(sx, sy);     // stat row 0 (out row y0)
    stB[t] = make_float2(sq, sxy);
    {
        float nx[6], ny[6];
#pragma unroll
        for (int i = 0; i < 6; ++i) {   // rows y0+7 .. y0+12
            nx[i] = xp[(7 + i) * W];
            ny[i] = ap[(7 + i) * W];
        }
#pragma unroll
        for (int i = 1; i < 7; ++i) VSTEP(i - 1, i, nx[i - 1], ny[i - 1]);
    }

    // ---------------- main loop: horizontal(c) then vertical(c+1) ----------------
    int c = 0;
    while (true) {
        __syncthreads();   // stats of chunk c visible
        if (t < NSLOT) {
            // ---- plane A: sx, sy ----
            const float4* qa = (const float4*)(stA + r * P2 + c0);
            float4 a[8];
#pragma unroll
            for (int k = 0; k < 8; ++k) a[k] = qa[k];
            float vx[16], vy[16];
#pragma unroll
            for (int k = 0; k < 8; ++k) {
                vx[2 * k]     = a[k].x; vy[2 * k]     = a[k].y;
                vx[2 * k + 1] = a[k].z; vy[2 * k + 1] = a[k].w;
            }
            float S0[8], S1[8];
            float sA = ((vx[0] + vx[1]) + (vx[2] + vx[3])) + ((vx[4] + vx[5]) + vx[6]);
            float sB = ((vy[0] + vy[1]) + (vy[2] + vy[3])) + ((vy[4] + vy[5]) + vy[6]);
            S0[0] = sA; S1[0] = sB;
#pragma unroll
            for (int j = 1; j < 8; ++j) {
                sA += vx[j + 6] - vx[j - 1]; S0[j] = sA;
                sB += vy[j + 6] - vy[j - 1]; S1[j] = sB;
            }
            // ---- plane B: sq, sxy (slide inline, math fused) ----
            const float4* qb = (const float4*)(stB + r * P2 + c0);
            float4 b[8];
#pragma unroll
            for (int k = 0; k < 8; ++k) b[k] = qb[k];
            float vq[16], vw[16];
#pragma unroll
            for (int k = 0; k < 8; ++k) {
                vq[2 * k]     = b[k].x; vw[2 * k]     = b[k].y;
                vq[2 * k + 1] = b[k].z; vw[2 * k + 1] = b[k].w;
            }
            float s2 = ((vq[0] + vq[1]) + (vq[2] + vq[3])) + ((vq[4] + vq[5]) + vq[6]);
            float s3 = ((vw[0] + vw[1]) + (vw[2] + vw[3])) + ((vw[4] + vw[5]) + vw[6]);
#pragma unroll
            for (int j = 0; j < 8; ++j) {
                if (j) {
                    s2 += vq[j + 6] - vq[j - 1];
                    s3 += vw[j + 6] - vw[j - 1];
                }
                const float Sx = S0[j], Sy = S1[j];
                const float Sq = s2, Sxy = s3;
                const float p  = Sx * Sy;
                const float qq = fmaf(Sx, Sx, Sy * Sy);
                const float n1 = fmaf(2.f, p, C1B);
                const float n2 = fmaf(98.f, Sxy, fmaf(-2.f, p, C2B));
                const float d1 = qq + C1B;
                const float d2 = fmaf(49.f, Sq, C2B - qq);
                const float s  = (n1 * n2) * __builtin_amdgcn_rcpf(d1 * d2);
                acc = (j < nmax) ? acc + s : acc;   // select, don't scale (garbage may be NaN)
            }
        }
        if (++c == nch) break;
        __syncthreads();   // horizontal reads done; safe to overwrite stats
        {
            const int rb = 7 * c + 6;    // entering rows (rel. to y0): rb..rb+6
            float nx[7], ny[7];
#pragma unroll
            for (int i = 0; i < 7; ++i) {
                nx[i] = xp[(rb + i) * W];
                ny[i] = ap[(rb + i) * W];
            }
            // ring slot for out row 7c+i is (i+6)%7 -- static per unrolled step
            VSTEP(6, 0, nx[0], ny[0]);
            VSTEP(0, 1, nx[1], ny[1]);
            VSTEP(1, 2, nx[2], ny[2]);
            VSTEP(2, 3, nx[3], ny[3]);
            VSTEP(3, 4, nx[4], ny[4]);
            VSTEP(4, 5, nx[5], ny[5]);
            VSTEP(5, 6, nx[6], ny[6]);
        }
    }

    // ---------------- block reduction ----------------
    const float wsum = wave_reduce(acc);
    if ((t & 63) == 0) red[t >> 6] = wsum;
    __syncthreads();
    if (t == 0) {
        partials[blockIdx.x + NSTRIP * blockIdx.y] =
            ((red[0] + red[1]) + (red[2] + red[3])) + (red[4] + red[5]);
    }
}

__global__ __launch_bounds__(1024) void ssim_finalize(const float* __restrict__ partials,
                                                      float* __restrict__ out) {
    __shared__ double red[1024];
    const int t = threadIdx.x;
    double s = 0.0;
    for (int i = t; i < NBLK; i += 1024) s += (double)partials[i];
    red[t] = s;
    __syncthreads();
#pragma unroll
    for (int off = 512; off > 0; off >>= 1) {
        if (t < off) red[t] += red[t + off];
        __syncthreads();
    }
    if (t == 0) out[0] = (float)(red[0] / ((double)NIMG * OWIDTH * OWIDTH));
}

extern "C" void kernel_launch(void* const* d_in, const int* in_sizes, int n_in,
                              void* d_out, int out_size, void* d_ws, size_t ws_size,
                              hipStream_t stream) {
    const float* pred = (const float*)d_in[0];
    const float* act  = (const float*)d_in[1];
    float* partials = (float*)d_ws;              // NBLK floats, fully overwritten each call
    dim3 grid(NSTRIP, NIMG);
    ssim_main<<<grid, 384, 0, stream>>>(pred, act, partials);
    ssim_finalize<<<1, 1024, 0, stream>>>(partials, (float*)d_out);
}

// Round 2
// 169.501 us; speedup vs baseline: 1.0543x; 1.0543x over previous
//
#include <hip/hip_runtime.h>

// ---------------------------------------------------------------------------
// SSIM R4. R3 post-mortem: inputs (151 MB) are L3-resident -> NOT HBM-bound.
// R3 was latency-bound: 1024 blocks (4/CU), VALUBusy 28%, Occupancy 28%,
// 2.13M LDS bank conflicts, global latency exposed between barriers.
// R4:
//  * SY=18, CH=6, 21 strips x 128 imgs = 2688 blocks (10.5/CU). 378=63*6
//    exactly -> no masking anywhere; 3 chunks/strip fully unrolled with
//    static ring slots (no rotation movs, no scratch).
//  * T14 prefetch: next chunk's 12 global loads issued BEFORE barrier +
//    horizontal phase; consumed after the write barrier -> latency hidden.
//  * Horizontal groups of 6 outputs (stride 12 words): lanes tile all 8
//    bank-quads uniformly -> conflict-free ds_read_b128 (8-pass minimum).
//    P2=386 (row stride 772 == 4 mod 32). LDS 44.5 -> 37.0 KB.
//  * Lane activity: vertical 384/384, horizontal 378/384.
//  * SSIM math / summation order bit-identical to R3 (absmax 0.0).
// Predicted: ssim_main ~34 us, conflicts <0.2M, VALUBusy ~55%, occ ~55%.
// ---------------------------------------------------------------------------

#define H 384
#define W 384
#define OWIDTH 378          // valid output rows/cols per image
#define NIMG 128
#define CH 6                // out rows per chunk
#define P2 386              // LDS row pitch in float2 (>=384; stride 4 mod 32)
#define PLANE (CH * P2)     // 2316 float2 per plane
#define SY 18               // out rows per strip (3 chunks)
#define NSTRIP 21           // 21*18 = 378 exactly
#define NBLK (NSTRIP * NIMG)  // 2688 partials
#define NGRP 63             // horizontal groups of 6 outputs (63*6 = 378 exact)
#define NSLOT (NGRP * CH)   // 378 active threads in horizontal phase

__device__ __forceinline__ float wave_reduce(float v) {
#pragma unroll
    for (int off = 32; off > 0; off >>= 1) v += __shfl_down(v, off, 64);
    return v;
}

// Vertical sliding step: retire ring slot SLOT, insert new row (XN,YN),
// update 4 running stats, store stat row LR to LDS. SLOT/LR compile-time.
#define VSTEP(SLOT, LR, XN, YN) do {                                      \
    const float xo = xv[SLOT], yo = yv[SLOT];                             \
    const float xn = (XN), yn = (YN);                                     \
    sx += xn - xo; sy += yn - yo;                                         \
    sq = fmaf(xn, xn, fmaf(yn, yn, fmaf(-xo, xo, fmaf(-yo, yo, sq))));    \
    sxy = fmaf(xn, yn, fmaf(-xo, yo, sxy));                               \
    xv[SLOT] = xn; yv[SLOT] = yn;                                         \
    stA[(LR) * P2 + t] = make_float2(sx, sy);                             \
    stB[(LR) * P2 + t] = make_float2(sq, sxy);                            \
} while (0)

// Horizontal phase over the CH x 378 stat tile currently in LDS.
// Thread (r,g) produces outputs cols 6g..6g+5 of tile row r.
#define HORIZ do {                                                              \
    if (t < NSLOT) {                                                            \
        const float4* qa = (const float4*)(stA + hoff);                         \
        const float4 a0 = qa[0], a1 = qa[1], a2 = qa[2],                        \
                     a3 = qa[3], a4 = qa[4], a5 = qa[5];                        \
        const float vx[12] = {a0.x, a0.z, a1.x, a1.z, a2.x, a2.z,               \
                              a3.x, a3.z, a4.x, a4.z, a5.x, a5.z};              \
        const float vy[12] = {a0.y, a0.w, a1.y, a1.w, a2.y, a2.w,               \
                              a3.y, a3.w, a4.y, a4.w, a5.y, a5.w};              \
        float S0[6], S1[6];                                                     \
        float sA = ((vx[0] + vx[1]) + (vx[2] + vx[3])) + ((vx[4] + vx[5]) + vx[6]); \
        float sB = ((vy[0] + vy[1]) + (vy[2] + vy[3])) + ((vy[4] + vy[5]) + vy[6]); \
        S0[0] = sA; S1[0] = sB;                                                 \
        _Pragma("unroll")                                                       \
        for (int j = 1; j < 6; ++j) {                                           \
            sA += vx[j + 6] - vx[j - 1]; S0[j] = sA;                            \
            sB += vy[j + 6] - vy[j - 1]; S1[j] = sB;                            \
        }                                                                       \
        const float4* qb = (const float4*)(stB + hoff);                         \
        const float4 b0 = qb[0], b1 = qb[1], b2 = qb[2],                        \
                     b3 = qb[3], b4 = qb[4], b5 = qb[5];                        \
        const float vq[12] = {b0.x, b0.z, b1.x, b1.z, b2.x, b2.z,               \
                              b3.x, b3.z, b4.x, b4.z, b5.x, b5.z};              \
        const float vw[12] = {b0.y, b0.w, b1.y, b1.w, b2.y, b2.w,               \
                              b3.y, b3.w, b4.y, b4.w, b5.y, b5.w};              \
        float s2 = ((vq[0] + vq[1]) + (vq[2] + vq[3])) + ((vq[4] + vq[5]) + vq[6]); \
        float s3 = ((vw[0] + vw[1]) + (vw[2] + vw[3])) + ((vw[4] + vw[5]) + vw[6]); \
        _Pragma("unroll")                                                       \
        for (int j = 0; j < 6; ++j) {                                           \
            if (j) {                                                            \
                s2 += vq[j + 6] - vq[j - 1];                                    \
                s3 += vw[j + 6] - vw[j - 1];                                    \
            }                                                                   \
            const float Sx = S0[j], Sy = S1[j];                                 \
            const float Sq = s2, Sxy = s3;                                      \
            const float p  = Sx * Sy;                                           \
            const float qq = fmaf(Sx, Sx, Sy * Sy);                             \
            const float n1 = fmaf(2.f, p, C1B);                                 \
            const float n2 = fmaf(98.f, Sxy, fmaf(-2.f, p, C2B));               \
            const float d1 = qq + C1B;                                          \
            const float d2 = fmaf(49.f, Sq, C2B - qq);                          \
            const float s  = (n1 * n2) * __builtin_amdgcn_rcpf(d1 * d2);        \
            acc += s;                                                           \
        }                                                                       \
    }                                                                           \
} while (0)

__global__ __launch_bounds__(384, 5) void ssim_main(const float* __restrict__ pred,
                                                    const float* __restrict__ act,
                                                    float* __restrict__ partials) {
    __shared__ __align__(16) float2 st[2 * PLANE];   // 37056 B
    __shared__ float red[6];

    const int t = threadIdx.x;
    const int y0 = blockIdx.x * SY;                  // <= 360; rows y0..y0+23 <= 383
    const size_t base = (size_t)blockIdx.y * (H * W);

    float2* const stA = st;
    float2* const stB = st + PLANE;

    const float* xp = pred + base + (size_t)y0 * W + t;
    const float* ap = act  + base + (size_t)y0 * W + t;

    // horizontal-phase constants
    const int r = t / NGRP;                 // 0..5 tile row (t<378)
    const int g = t - NGRP * r;             // 0..62 column group -> cols 6g..6g+5
    const int hoff = r * P2 + 6 * g;        // float2 offset; 16B-aligned
    const float C1B = 0.2401f;              // C1 * 49^2
    const float C2B = 2.1168f;              // C2 * 48*49
    float acc = 0.f;

    // ---------------- prologue: rows 0..11, stats rows 0..5 (chunk 0) ----------
    float xr[12], yr[12];
#pragma unroll
    for (int i = 0; i < 12; ++i) {
        xr[i] = xp[i * W];
        yr[i] = ap[i * W];
    }
    float xv[7], yv[7];
#pragma unroll
    for (int i = 0; i < 7; ++i) { xv[i] = xr[i]; yv[i] = yr[i]; }
    float sx = 0.f, sy = 0.f, sq = 0.f, sxy = 0.f;
#pragma unroll
    for (int i = 0; i < 7; ++i) {
        sx += xv[i]; sy += yv[i];
        sq = fmaf(xv[i], xv[i], fmaf(yv[i], yv[i], sq));
        sxy = fmaf(xv[i], yv[i], sxy);
    }
    stA[t] = make_float2(sx, sy);
    stB[t] = make_float2(sq, sxy);
    VSTEP(0, 1, xr[7],  yr[7]);
    VSTEP(1, 2, xr[8],  yr[8]);
    VSTEP(2, 3, xr[9],  yr[9]);
    VSTEP(3, 4, xr[10], yr[10]);
    VSTEP(4, 5, xr[11], yr[11]);
    // ring slots now hold rows [7,8,9,10,11,5,6]

    // ---------------- chunk 0: prefetch rows 12..17, horiz, vstep ----------------
    {
        float pfx[6], pfy[6];
#pragma unroll
        for (int i = 0; i < 6; ++i) {        // in flight across barrier+HORIZ
            pfx[i] = xp[(12 + i) * W];
            pfy[i] = ap[(12 + i) * W];
        }
        __syncthreads();                     // chunk-0 stats visible
        HORIZ;                               // out rows y0..y0+5
        __syncthreads();                     // reads done; safe to overwrite
        VSTEP(5, 0, pfx[0], pfy[0]);         // retire rows 5..10
        VSTEP(6, 1, pfx[1], pfy[1]);
        VSTEP(0, 2, pfx[2], pfy[2]);
        VSTEP(1, 3, pfx[3], pfy[3]);
        VSTEP(2, 4, pfx[4], pfy[4]);
        VSTEP(3, 5, pfx[5], pfy[5]);
        // ring slots now hold rows [14,15,16,17,11,12,13]
    }

    // ---------------- chunk 1: prefetch rows 18..23, horiz, vstep ----------------
    {
        float pfx[6], pfy[6];
#pragma unroll
        for (int i = 0; i < 6; ++i) {
            pfx[i] = xp[(18 + i) * W];
            pfy[i] = ap[(18 + i) * W];
        }
        __syncthreads();                     // chunk-1 stats visible
        HORIZ;                               // out rows y0+6..y0+11
        __syncthreads();
        VSTEP(4, 0, pfx[0], pfy[0]);         // retire rows 11..16
        VSTEP(5, 1, pfx[1], pfy[1]);
        VSTEP(6, 2, pfx[2], pfy[2]);
        VSTEP(0, 3, pfx[3], pfy[3]);
        VSTEP(1, 4, pfx[4], pfy[4]);
        VSTEP(2, 5, pfx[5], pfy[5]);
    }

    // ---------------- chunk 2: horiz only ----------------
    __syncthreads();                         // chunk-2 stats visible
    HORIZ;                                   // out rows y0+12..y0+17

    // ---------------- block reduction ----------------
    const float wsum = wave_reduce(acc);
    if ((t & 63) == 0) red[t >> 6] = wsum;
    __syncthreads();
    if (t == 0) {
        partials[blockIdx.x + NSTRIP * blockIdx.y] =
            ((red[0] + red[1]) + (red[2] + red[3])) + (red[4] + red[5]);
    }
}

__global__ __launch_bounds__(1024) void ssim_finalize(const float* __restrict__ partials,
                                                      float* __restrict__ out) {
    __shared__ double red[1024];
    const int t = threadIdx.x;
    double s = 0.0;
    for (int i = t; i < NBLK; i += 1024) s += (double)partials[i];
    red[t] = s;
    __syncthreads();
#pragma unroll
    for (int off = 512; off > 0; off >>= 1) {
        if (t < off) red[t] += red[t + off];
        __syncthreads();
    }
    if (t == 0) out[0] = (float)(red[0] / ((double)NIMG * OWIDTH * OWIDTH));
}

extern "C" void kernel_launch(void* const* d_in, const int* in_sizes, int n_in,
                              void* d_out, int out_size, void* d_ws, size_t ws_size,
                              hipStream_t stream) {
    const float* pred = (const float*)d_in[0];
    const float* act  = (const float*)d_in[1];
    float* partials = (float*)d_ws;          // NBLK floats, fully overwritten each call
    dim3 grid(NSTRIP, NIMG);
    ssim_main<<<grid, 384, 0, stream>>>(pred, act, partials);
    ssim_finalize<<<1, 1024, 0, stream>>>(partials, (float*)d_out);
}